// Round 4
// baseline (282.487 us; speedup 1.0000x reference)
//
#include <hip/hip_runtime.h>
#include <stdint.h>

#define BB 2
#define NN 8192
#define DD 1024
#define KK 1024
#define NHEAD 16
#define HDIM 64
#define KV_CHUNKS 32

using f32x4  = __attribute__((ext_vector_type(4))) float;
using bf16x8 = __attribute__((ext_vector_type(8))) short;

__device__ __forceinline__ unsigned short f2bf(float f) {
  union { float f; unsigned int u; } v; v.f = f;
  unsigned int r = v.u + 0x7fffu + ((v.u >> 16) & 1u);
  return (unsigned short)(r >> 16);
}
__device__ __forceinline__ float bf2f(unsigned short u) {
  union { unsigned int u; float f; } v; v.u = ((unsigned int)u) << 16;
  return v.f;
}

__device__ __forceinline__ void gload_lds16(const unsigned short* g, unsigned short* l) {
  __builtin_amdgcn_global_load_lds(
      (__attribute__((address_space(1))) void*)(const_cast<unsigned short*>(g)),
      (__attribute__((address_space(3))) void*)(l), 16, 0, 0);
}

// ---------------- fp32 -> bf16 convert ----------------
__global__ __launch_bounds__(256) void f32_to_bf16_k(const float* __restrict__ in,
                                                     unsigned short* __restrict__ out) {
  size_t i = ((size_t)blockIdx.x * 256 + threadIdx.x) * 8;
  float4 a = *(const float4*)(in + i);
  float4 b = *(const float4*)(in + i + 4);
  uint32_t p0 = (uint32_t)f2bf(a.x) | ((uint32_t)f2bf(a.y) << 16);
  uint32_t p1 = (uint32_t)f2bf(a.z) | ((uint32_t)f2bf(a.w) << 16);
  uint32_t p2 = (uint32_t)f2bf(b.x) | ((uint32_t)f2bf(b.y) << 16);
  uint32_t p3 = (uint32_t)f2bf(b.z) | ((uint32_t)f2bf(b.w) << 16);
  *(uint4*)(out + i) = make_uint4(p0, p1, p2, p3);
}

// ---------------- 256x256 8-phase GEMM (QKV fused): C = A[M,K] * B[N,K]^T ----------------
#define BAR  __builtin_amdgcn_s_barrier()
#define SB   __builtin_amdgcn_sched_barrier(0)
#define WLG  asm volatile("s_waitcnt lgkmcnt(0)" ::: "memory")
#define WVM4 asm volatile("s_waitcnt vmcnt(4)" ::: "memory")
#define WVM0 asm volatile("s_waitcnt vmcnt(0)" ::: "memory")

__global__ __launch_bounds__(512, 2) void gemm256_qkv(const unsigned short* __restrict__ A,
                                                      const unsigned short* __restrict__ Bw,
                                                      unsigned short* __restrict__ O0,
                                                      unsigned short* __restrict__ O1,
                                                      unsigned short* __restrict__ O2) {
  __shared__ unsigned short lds[2][2][2][128 * 64];  // [dbuf][A/B][half][128x64] = 128 KB
  const int t = threadIdx.x;
  const int lane = t & 63;
  const int w = t >> 6;
  const int wm = w >> 2;
  const int wn = w & 3;
  const int frow = lane & 15;
  const int g = lane >> 4;
  const int fx = frow & 7;
  // T1 XCD swizzle: 768 wgs, 96/XCD; each XCD owns 1.5 B-col-panels (B L2-resident),
  // bx varies fastest within an XCD chunk.
  const int id = blockIdx.y * 64 + blockIdx.x;
  const int swz = (id & 7) * 96 + (id >> 3);
  const int bx = swz & 63;
  const int by = swz >> 6;
  const int rowBase = bx * 256;
  const int colBase = by * 256;

  const int srow0 = t >> 3;
  const int ssw = ((t & 7) ^ (srow0 & 7)) * 8;
  const unsigned short* sA0 = A + (size_t)(rowBase + srow0) * KK + ssw;
  const unsigned short* sA1 = A + (size_t)(rowBase + 64 + srow0) * KK + ssw;
  const unsigned short* sB0 = Bw + (size_t)(colBase + srow0) * KK + ssw;
  const unsigned short* sB1 = Bw + (size_t)(colBase + 64 + srow0) * KK + ssw;

#define STAGE(db, ab, half, kt)                                                        \
  do {                                                                                 \
    gload_lds16(((ab) ? sB0 : sA0) + (size_t)(half) * 128 * KK + (size_t)(kt) * 64,    \
                &lds[db][ab][half][(0 * 512 + w * 64) * 8]);                           \
    gload_lds16(((ab) ? sB1 : sA1) + (size_t)(half) * 128 * KK + (size_t)(kt) * 64,    \
                &lds[db][ab][half][(1 * 512 + w * 64) * 8]);                           \
  } while (0)

  bf16x8 ar[4][2], br[4][2];
  f32x4 acc[8][4];
#pragma unroll
  for (int i = 0; i < 8; ++i)
#pragma unroll
    for (int j = 0; j < 4; ++j) acc[i][j] = (f32x4){0.f, 0.f, 0.f, 0.f};

#define LDA4(db, mih)                                                                  \
  _Pragma("unroll") for (int mi2 = 0; mi2 < 4; ++mi2)                                  \
  _Pragma("unroll") for (int kk2 = 0; kk2 < 2; ++kk2)                                  \
    ar[mi2][kk2] = *(const bf16x8*)((const char*)&lds[db][0][wm][0] +                  \
        ((mih) * 64 + mi2 * 16 + frow) * 128 + ((kk2 * 4 + g) ^ fx) * 16);

#define LDB2(db, nih)                                                                  \
  _Pragma("unroll") for (int ni2 = 0; ni2 < 2; ++ni2)                                  \
  _Pragma("unroll") for (int kk2 = 0; kk2 < 2; ++kk2)                                  \
    br[(nih) * 2 + ni2][kk2] = *(const bf16x8*)((const char*)&lds[db][1][wn >> 1][0] + \
        ((wn & 1) * 64 + (nih) * 32 + ni2 * 16 + frow) * 128 + ((kk2 * 4 + g) ^ fx) * 16);

#define MFMAQ(mih, nih)                                                                \
  __builtin_amdgcn_s_setprio(1);                                                      \
  _Pragma("unroll") for (int mi2 = 0; mi2 < 4; ++mi2)                                  \
  _Pragma("unroll") for (int ni2 = 0; ni2 < 2; ++ni2)                                  \
  _Pragma("unroll") for (int kk2 = 0; kk2 < 2; ++kk2)                                  \
    acc[(mih) * 4 + mi2][(nih) * 2 + ni2] = __builtin_amdgcn_mfma_f32_16x16x32_bf16(   \
        ar[mi2][kk2], br[(nih) * 2 + ni2][kk2],                                        \
        acc[(mih) * 4 + mi2][(nih) * 2 + ni2], 0, 0, 0);                               \
  __builtin_amdgcn_s_setprio(0);

  STAGE(0, 1, 0, 0); STAGE(0, 1, 1, 0);
  STAGE(0, 0, 0, 0); STAGE(0, 0, 1, 0);
  STAGE(1, 1, 0, 1); STAGE(1, 1, 1, 1);
  WVM4; BAR; SB;

#pragma unroll 1
  for (int i = 0; i < 8; ++i) {
    const bool full = (i < 7);
    const int kt1 = 2 * i + 1, kt2 = 2 * i + 2, kt3 = 2 * i + 3;
    LDA4(0, 0); LDB2(0, 0);
    STAGE(1, 0, 0, kt1);
    BAR; WLG; SB; MFMAQ(0, 0); BAR; SB;
    LDB2(0, 1);
    STAGE(1, 0, 1, kt1);
    BAR; WLG; SB; MFMAQ(0, 1); BAR; SB;
    LDA4(0, 1);
    if (full) STAGE(0, 1, 0, kt2);
    BAR; WLG; SB; MFMAQ(1, 0); BAR; SB;
    if (full) { STAGE(0, 1, 1, kt2); WVM4; } else { WVM0; }
    BAR; SB; MFMAQ(1, 1); BAR; SB;
    LDA4(1, 0); LDB2(1, 0);
    if (full) STAGE(0, 0, 0, kt2);
    BAR; WLG; SB; MFMAQ(0, 0); BAR; SB;
    LDB2(1, 1);
    if (full) STAGE(0, 0, 1, kt2);
    BAR; WLG; SB; MFMAQ(0, 1); BAR; SB;
    LDA4(1, 1);
    if (full) STAGE(1, 1, 0, kt3);
    BAR; WLG; SB; MFMAQ(1, 0); BAR; SB;
    if (full) { STAGE(1, 1, 1, kt3); WVM4; }
    BAR; SB; MFMAQ(1, 1); BAR; SB;
  }

  const int r0 = rowBase + wm * 128 + g * 4;
  const int ymat = by >> 2;  // 0=q,1=k,2=v
  unsigned short* dst = (ymat == 0) ? O0 : ((ymat == 1) ? O1 : O2);
  const int c0 = (by & 3) * 256 + wn * 64 + frow;
  const bool doElu = (ymat < 2);
#pragma unroll
  for (int mi = 0; mi < 8; ++mi)
#pragma unroll
    for (int j = 0; j < 4; ++j) {
      const size_t ro = (size_t)(r0 + mi * 16 + j) * DD;
#pragma unroll
      for (int ni = 0; ni < 4; ++ni) {
        float v = acc[mi][ni][j];
        if (doElu) v = (v > 0.f) ? (v + 1.f) : __expf(v);
        dst[ro + c0 + ni * 16] = f2bf(v);
      }
    }
#undef STAGE
#undef LDA4
#undef LDB2
#undef MFMAQ
}

// ---------------- m97-style 128x128 GEMM, f32 out (O-projection) ----------------
__global__ __launch_bounds__(256, 2) void gemm_bt_f32(const unsigned short* __restrict__ A,
                                                      const unsigned short* __restrict__ Bw,
                                                      float* __restrict__ Cp,
                                                      int M, int N, int K) {
  constexpr int BM = 128, BN = 128, BK = 64;
  __shared__ unsigned short As[BM * BK];
  __shared__ unsigned short Bs[BN * BK];
  const int t = threadIdx.x;
  const int lane = t & 63;
  const int w = t >> 6;
  const int wr = w >> 1, wc = w & 1;
  // T1 XCD swizzle: 1024 wgs, 128/XCD; each XCD owns one B col-panel.
  const int id = blockIdx.y * gridDim.x + blockIdx.x;
  const int swz = (id & 7) * 128 + (id >> 3);
  const int rowBase = (swz & 127) * BM;
  const int colBase = (swz >> 7) * BN;

  f32x4 acc[4][4];
#pragma unroll
  for (int i = 0; i < 4; ++i)
#pragma unroll
    for (int j = 0; j < 4; ++j) acc[i][j] = (f32x4){0.f, 0.f, 0.f, 0.f};

  const int sr = t >> 3;
  const int sc = (t & 7) * 8;
  const unsigned short* gA = A + (size_t)(rowBase + sr) * K + sc;
  const unsigned short* gB = Bw + (size_t)(colBase + sr) * K + sc;

  for (int k0 = 0; k0 < K; k0 += BK) {
#pragma unroll
    for (int i = 0; i < 4; ++i) {
      gload_lds16(gA + (size_t)i * 32 * K + k0, As + (i * 256 + w * 64) * 8);
      gload_lds16(gB + (size_t)i * 32 * K + k0, Bs + (i * 256 + w * 64) * 8);
    }
    __syncthreads();
#pragma unroll
    for (int kk = 0; kk < BK; kk += 32) {
      bf16x8 af[4], bfv[4];
#pragma unroll
      for (int mi = 0; mi < 4; ++mi)
        af[mi] = *(const bf16x8*)(As + (wr * 64 + mi * 16 + (lane & 15)) * BK + kk + (lane >> 4) * 8);
#pragma unroll
      for (int ni = 0; ni < 4; ++ni)
        bfv[ni] = *(const bf16x8*)(Bs + (wc * 64 + ni * 16 + (lane & 15)) * BK + kk + (lane >> 4) * 8);
#pragma unroll
      for (int mi = 0; mi < 4; ++mi)
#pragma unroll
        for (int ni = 0; ni < 4; ++ni)
          acc[mi][ni] = __builtin_amdgcn_mfma_f32_16x16x32_bf16(af[mi], bfv[ni], acc[mi][ni], 0, 0, 0);
    }
    __syncthreads();
  }

  const int r0 = rowBase + wr * 64 + ((lane >> 4) << 2);
  const int c0 = colBase + wc * 64 + (lane & 15);
#pragma unroll
  for (int mi = 0; mi < 4; ++mi)
#pragma unroll
    for (int j = 0; j < 4; ++j) {
      const size_t rowOff = (size_t)(r0 + mi * 16 + j) * N;
#pragma unroll
      for (int ni = 0; ni < 4; ++ni)
        Cp[rowOff + c0 + ni * 16] = acc[mi][ni][j];
    }
}

// ---------------- kv partials: kv[b,h,d,m] = sum_n k*v ; ksum[b,h,d] ----------------
__global__ __launch_bounds__(256) void kv_partial(const unsigned short* __restrict__ Kb,
                                                  const unsigned short* __restrict__ Vb,
                                                  float* __restrict__ kvp,
                                                  float* __restrict__ ksp) {
  __shared__ unsigned short ks[16][64];
  __shared__ float vsf[16][64];
  const int blk = blockIdx.x;
  const int c = blk % KV_CHUNKS;
  const int h = (blk / KV_CHUNKS) % NHEAD;
  const int b = blk / (KV_CHUNKS * NHEAD);
  const int chunkLen = NN / KV_CHUNKS;  // 256
  const int t = threadIdx.x;
  const int d = t >> 2;
  const int mq = (t & 3) * 16;
  float acc[16] = {};
  float sk = 0.f;
  const size_t base = ((size_t)b * NN + (size_t)c * chunkLen) * DD + h * HDIM;
  const int half = t >> 7;
  const int tt = t & 127;
  const int rr = tt >> 3;
  const int cc = (tt & 7) * 8;
  const unsigned short* src0 = (half ? Vb : Kb) + base + (size_t)rr * DD + cc;
  for (int n0 = 0; n0 < chunkLen; n0 += 16) {
    uint4 raw = *(const uint4*)(src0 + (size_t)n0 * DD);
    if (half == 0) {
      *(uint4*)&ks[rr][cc] = raw;
    } else {
      const unsigned short* pr = (const unsigned short*)&raw;
      float4 f0, f1;
      f0.x = bf2f(pr[0]); f0.y = bf2f(pr[1]); f0.z = bf2f(pr[2]); f0.w = bf2f(pr[3]);
      f1.x = bf2f(pr[4]); f1.y = bf2f(pr[5]); f1.z = bf2f(pr[6]); f1.w = bf2f(pr[7]);
      *(float4*)&vsf[rr][cc] = f0;
      *(float4*)&vsf[rr][cc + 4] = f1;
    }
    __syncthreads();
#pragma unroll
    for (int nn = 0; nn < 16; ++nn) {
      float kd = bf2f(ks[nn][d]);
      sk += kd;
      const float4* vrow = (const float4*)&vsf[nn][mq];
#pragma unroll
      for (int j4 = 0; j4 < 4; ++j4) {
        float4 vv = vrow[j4];
        acc[j4 * 4 + 0] += kd * vv.x;
        acc[j4 * 4 + 1] += kd * vv.y;
        acc[j4 * 4 + 2] += kd * vv.z;
        acc[j4 * 4 + 3] += kd * vv.w;
      }
    }
    __syncthreads();
  }
  float* dst = kvp + (size_t)blk * 4096 + d * 64 + mq;
#pragma unroll
  for (int j = 0; j < 16; ++j) dst[j] = acc[j];
  if ((t & 3) == 0) ksp[(size_t)blk * 64 + d] = sk;
}

// ---------------- kv final: bf16 B-matrix kvb[bh][96][64]; row 64 = ksum ----------------
__global__ __launch_bounds__(256) void kv_final(const float* __restrict__ kvp,
                                                const float* __restrict__ ksp,
                                                unsigned short* __restrict__ kvb) {
  const int bh = blockIdx.x;
  const int t = threadIdx.x;
  __shared__ float kvs[4096];
#pragma unroll
  for (int e0 = 0; e0 < 4096; e0 += 256) {
    float s = 0.f;
    for (int cI = 0; cI < KV_CHUNKS; ++cI)
      s += kvp[((size_t)bh * KV_CHUNKS + cI) * 4096 + e0 + t];
    kvs[e0 + t] = s;
  }
  __syncthreads();
  unsigned short* dst = kvb + (size_t)bh * (96 * 64);
#pragma unroll
  for (int e0 = 0; e0 < 4096; e0 += 256) {
    int e = e0 + t;
    dst[e] = f2bf(kvs[(e & 63) * 64 + (e >> 6)]);
  }
  if (t < 64) {
    float s = 0.f;
    for (int cI = 0; cI < KV_CHUNKS; ++cI)
      s += ksp[((size_t)bh * KV_CHUNKS + cI) * 64 + t];
    dst[64 * 64 + t] = f2bf(s);
  }
  for (int e0 = 65 * 64; e0 < 96 * 64; e0 += 256) {
    int e = e0 + t;
    if (e < 96 * 64) dst[e] = 0;
  }
}

// ---------------- attn via MFMA ----------------
__global__ __launch_bounds__(256) void attn_mfma(const unsigned short* __restrict__ Qb,
                                                 const unsigned short* __restrict__ kvb,
                                                 unsigned short* __restrict__ Ob) {
  __shared__ unsigned short Bs[96 * 64];
  __shared__ unsigned short Qs[64 * 64];
  const int t = threadIdx.x;
  const int lane = t & 63;
  const int w = t >> 6;
  const int bh = blockIdx.y;
  const int b = bh >> 4;
  const int h = bh & 15;
  const int rowBase = blockIdx.x * 64;

  const unsigned short* bsrc = kvb + (size_t)bh * (96 * 64);
#pragma unroll
  for (int r = 0; r < 3; ++r) {
    int ci = r * 256 + t;
    int row = ci >> 3, ch = ci & 7;
    gload_lds16(bsrc + row * 64 + (ch ^ (row & 7)) * 8, Bs + ci * 8);
  }
  const int sr = t >> 3, ch0 = t & 7;
#pragma unroll
  for (int i = 0; i < 2; ++i) {
    int row = i * 32 + sr;
    const unsigned short* src =
        Qb + ((size_t)(b * NN + rowBase + row)) * DD + h * HDIM + (ch0 ^ (row & 7)) * 8;
    gload_lds16(src, Qs + row * 64 + ch0 * 8);
  }
  __syncthreads();

  const int frow = lane & 15;
  const int g = lane >> 4;
  bf16x8 a[2];
#pragma unroll
  for (int kk = 0; kk < 2; ++kk)
    a[kk] = *(const bf16x8*)(Qs + (w * 16 + frow) * 64 + ((kk * 4 + g) ^ (lane & 7)) * 8);

  f32x4 acc[5];
#pragma unroll
  for (int c = 0; c < 5; ++c) acc[c] = (f32x4){0.f, 0.f, 0.f, 0.f};
#pragma unroll
  for (int c = 0; c < 5; ++c) {
#pragma unroll
    for (int kk = 0; kk < 2; ++kk) {
      bf16x8 bf = *(const bf16x8*)(Bs + (c * 16 + frow) * 64 + ((kk * 4 + g) ^ (lane & 7)) * 8);
      acc[c] = __builtin_amdgcn_mfma_f32_16x16x32_bf16(a[kk], bf, acc[c], 0, 0, 0);
    }
  }

  float rden[4];
#pragma unroll
  for (int j = 0; j < 4; ++j) {
    float den = __shfl(acc[4][j], g * 16, 64);
    rden[j] = 1.f / (den + 1e-6f);
  }
  const size_t obase = ((size_t)(b * NN + rowBase + w * 16 + g * 4)) * DD + h * HDIM + frow;
#pragma unroll
  for (int c = 0; c < 4; ++c)
#pragma unroll
    for (int j = 0; j < 4; ++j)
      Ob[obase + (size_t)j * DD + c * 16] = f2bf(acc[c][j] * rden[j]);
}

// ---------------- launch ----------------
extern "C" void kernel_launch(void* const* d_in, const int* in_sizes, int n_in,
                              void* d_out, int out_size, void* d_ws, size_t ws_size,
                              hipStream_t stream) {
  const float* x  = (const float*)d_in[0];
  const float* Wq = (const float*)d_in[1];
  const float* Wk = (const float*)d_in[2];
  const float* Wv = (const float*)d_in[3];
  const float* Wo = (const float*)d_in[4];
  float* out = (float*)d_out;

  char* ws = (char*)d_ws;
  size_t off = 0;
  auto alloc = [&](size_t bytes) -> char* {
    char* p = ws + off;
    off += (bytes + 255) & ~(size_t)255;
    return p;
  };
  const size_t xN = (size_t)BB * NN * DD;  // 16777216
  unsigned short* xb   = (unsigned short*)alloc(xN * 2);
  unsigned short* qb   = (unsigned short*)alloc(xN * 2);
  unsigned short* kb   = (unsigned short*)alloc(xN * 2);
  unsigned short* vb   = (unsigned short*)alloc(xN * 2);
  unsigned short* wqkv = (unsigned short*)alloc((size_t)3 * DD * DD * 2);
  unsigned short* wob  = (unsigned short*)alloc((size_t)DD * DD * 2);
  float* ksp = (float*)alloc((size_t)BB * NHEAD * KV_CHUNKS * 64 * 4);
  unsigned short* kvb = (unsigned short*)alloc((size_t)BB * NHEAD * 96 * 64 * 2);
  // kvp (16.8 MB) aliases xb (33.5 MB): xb dead after QKV GEMM; kvp consumed by
  // kv_final before attn writes ob (= xb) — all stream-ordered.
  float* kvp = (float*)xb;
  unsigned short* ob = xb;

  f32_to_bf16_k<<<(int)(xN / (256 * 8)), 256, 0, stream>>>(x, xb);
  f32_to_bf16_k<<<(DD * DD) / (256 * 8), 256, 0, stream>>>(Wq, wqkv);
  f32_to_bf16_k<<<(DD * DD) / (256 * 8), 256, 0, stream>>>(Wk, wqkv + (size_t)DD * DD);
  f32_to_bf16_k<<<(DD * DD) / (256 * 8), 256, 0, stream>>>(Wv, wqkv + (size_t)2 * DD * DD);
  f32_to_bf16_k<<<(DD * DD) / (256 * 8), 256, 0, stream>>>(Wo, wob);

  dim3 gq(64, 12);  // M/256 x 3072/256
  gemm256_qkv<<<gq, 512, 0, stream>>>(xb, wqkv, qb, kb, vb);

  kv_partial<<<BB * NHEAD * KV_CHUNKS, 256, 0, stream>>>(kb, vb, kvp, ksp);
  kv_final<<<BB * NHEAD, 256, 0, stream>>>(kvp, ksp, kvb);

  dim3 ga(NN / 64, BB * NHEAD);
  attn_mfma<<<ga, 256, 0, stream>>>(qb, kvb, ob);

  dim3 go(128, 8);  // m97 structure: M/128 x 1024/128
  gemm_bt_f32<<<go, 256, 0, stream>>>(ob, wob, out, BB * NN, DD, DD);
}

// Round 5
// 233.742 us; speedup vs baseline: 1.2085x; 1.2085x over previous
//
#include <hip/hip_runtime.h>
#include <stdint.h>

#define BB 2
#define NN 8192
#define DD 1024
#define KK 1024
#define NHEAD 16
#define HDIM 64
#define KV_CHUNKS 32

using f32x4  = __attribute__((ext_vector_type(4))) float;
using bf16x8 = __attribute__((ext_vector_type(8))) short;

__device__ __forceinline__ unsigned short f2bf(float f) {
  union { float f; unsigned int u; } v; v.f = f;
  unsigned int r = v.u + 0x7fffu + ((v.u >> 16) & 1u);
  return (unsigned short)(r >> 16);
}
__device__ __forceinline__ float bf2f(unsigned short u) {
  union { unsigned int u; float f; } v; v.u = ((unsigned int)u) << 16;
  return v.f;
}

__device__ __forceinline__ void gload_lds16(const unsigned short* g, unsigned short* l) {
  __builtin_amdgcn_global_load_lds(
      (__attribute__((address_space(1))) void*)(const_cast<unsigned short*>(g)),
      (__attribute__((address_space(3))) void*)(l), 16, 0, 0);
}

// ---------------- fp32 -> bf16 convert ----------------
__global__ __launch_bounds__(256) void f32_to_bf16_k(const float* __restrict__ in,
                                                     unsigned short* __restrict__ out) {
  size_t i = ((size_t)blockIdx.x * 256 + threadIdx.x) * 8;
  float4 a = *(const float4*)(in + i);
  float4 b = *(const float4*)(in + i + 4);
  uint32_t p0 = (uint32_t)f2bf(a.x) | ((uint32_t)f2bf(a.y) << 16);
  uint32_t p1 = (uint32_t)f2bf(a.z) | ((uint32_t)f2bf(a.w) << 16);
  uint32_t p2 = (uint32_t)f2bf(b.x) | ((uint32_t)f2bf(b.y) << 16);
  uint32_t p3 = (uint32_t)f2bf(b.z) | ((uint32_t)f2bf(b.w) << 16);
  *(uint4*)(out + i) = make_uint4(p0, p1, p2, p3);
}

// ---------------- 256x256 8-phase GEMM (QKV fused): C = A[M,K] * B[N,K]^T ----------------
// NO XCD swizzle: default round-robin is optimal for tall-skinny (R4 post-mortem).
#define BAR  __builtin_amdgcn_s_barrier()
#define SB   __builtin_amdgcn_sched_barrier(0)
#define WLG  asm volatile("s_waitcnt lgkmcnt(0)" ::: "memory")
#define WVM4 asm volatile("s_waitcnt vmcnt(4)" ::: "memory")
#define WVM2 asm volatile("s_waitcnt vmcnt(2)" ::: "memory")
#define WVM0 asm volatile("s_waitcnt vmcnt(0)" ::: "memory")

__global__ __launch_bounds__(512, 2) void gemm256_qkv(const unsigned short* __restrict__ A,
                                                      const unsigned short* __restrict__ Bw,
                                                      unsigned short* __restrict__ O0,
                                                      unsigned short* __restrict__ O1,
                                                      unsigned short* __restrict__ O2) {
  __shared__ unsigned short lds[2][2][2][128 * 64];  // [dbuf][A/B][half][128x64] = 128 KB
  const int t = threadIdx.x;
  const int lane = t & 63;
  const int w = t >> 6;
  const int wm = w >> 2;
  const int wn = w & 3;
  const int frow = lane & 15;
  const int g = lane >> 4;
  const int fx = frow & 7;
  const int rowBase = blockIdx.x * 256;
  const int colBase = blockIdx.y * 256;

  const int srow0 = t >> 3;
  const int ssw = ((t & 7) ^ (srow0 & 7)) * 8;
  const unsigned short* sA0 = A + (size_t)(rowBase + srow0) * KK + ssw;
  const unsigned short* sA1 = A + (size_t)(rowBase + 64 + srow0) * KK + ssw;
  const unsigned short* sB0 = Bw + (size_t)(colBase + srow0) * KK + ssw;
  const unsigned short* sB1 = Bw + (size_t)(colBase + 64 + srow0) * KK + ssw;

#define STAGE(db, ab, half, kt)                                                        \
  do {                                                                                 \
    gload_lds16(((ab) ? sB0 : sA0) + (size_t)(half) * 128 * KK + (size_t)(kt) * 64,    \
                &lds[db][ab][half][(0 * 512 + w * 64) * 8]);                           \
    gload_lds16(((ab) ? sB1 : sA1) + (size_t)(half) * 128 * KK + (size_t)(kt) * 64,    \
                &lds[db][ab][half][(1 * 512 + w * 64) * 8]);                           \
  } while (0)

  bf16x8 ar[4][2], br[4][2];
  f32x4 acc[8][4];
#pragma unroll
  for (int i = 0; i < 8; ++i)
#pragma unroll
    for (int j = 0; j < 4; ++j) acc[i][j] = (f32x4){0.f, 0.f, 0.f, 0.f};

#define LDA4(db, mih)                                                                  \
  _Pragma("unroll") for (int mi2 = 0; mi2 < 4; ++mi2)                                  \
  _Pragma("unroll") for (int kk2 = 0; kk2 < 2; ++kk2)                                  \
    ar[mi2][kk2] = *(const bf16x8*)((const char*)&lds[db][0][wm][0] +                  \
        ((mih) * 64 + mi2 * 16 + frow) * 128 + ((kk2 * 4 + g) ^ fx) * 16);

#define LDB2(db, nih)                                                                  \
  _Pragma("unroll") for (int ni2 = 0; ni2 < 2; ++ni2)                                  \
  _Pragma("unroll") for (int kk2 = 0; kk2 < 2; ++kk2)                                  \
    br[(nih) * 2 + ni2][kk2] = *(const bf16x8*)((const char*)&lds[db][1][wn >> 1][0] + \
        ((wn & 1) * 64 + (nih) * 32 + ni2 * 16 + frow) * 128 + ((kk2 * 4 + g) ^ fx) * 16);

#define MFMAQ(mih, nih)                                                                \
  __builtin_amdgcn_s_setprio(1);                                                      \
  _Pragma("unroll") for (int mi2 = 0; mi2 < 4; ++mi2)                                  \
  _Pragma("unroll") for (int ni2 = 0; ni2 < 2; ++ni2)                                  \
  _Pragma("unroll") for (int kk2 = 0; kk2 < 2; ++kk2)                                  \
    acc[(mih) * 4 + mi2][(nih) * 2 + ni2] = __builtin_amdgcn_mfma_f32_16x16x32_bf16(   \
        ar[mi2][kk2], br[(nih) * 2 + ni2][kk2],                                        \
        acc[(mih) * 4 + mi2][(nih) * 2 + ni2], 0, 0, 0);                               \
  __builtin_amdgcn_s_setprio(0);

  STAGE(0, 1, 0, 0); STAGE(0, 1, 1, 0);
  STAGE(0, 0, 0, 0); STAGE(0, 0, 1, 0);
  STAGE(1, 1, 0, 1); STAGE(1, 1, 1, 1);
  WVM4; BAR; SB;

#pragma unroll 1
  for (int i = 0; i < 8; ++i) {
    const bool full = (i < 7);
    const int kt1 = 2 * i + 1, kt2 = 2 * i + 2, kt3 = 2 * i + 3;
    LDA4(0, 0); LDB2(0, 0);
    STAGE(1, 0, 0, kt1);
    BAR; WLG; SB; MFMAQ(0, 0); BAR; SB;
    LDB2(0, 1);
    STAGE(1, 0, 1, kt1);
    BAR; WLG; SB; MFMAQ(0, 1); BAR; SB;
    LDA4(0, 1);
    if (full) STAGE(0, 1, 0, kt2);
    BAR; WLG; SB; MFMAQ(1, 0); BAR; SB;
    if (full) { STAGE(0, 1, 1, kt2); WVM4; } else { WVM0; }
    BAR; SB; MFMAQ(1, 1); BAR; SB;
    LDA4(1, 0); LDB2(1, 0);
    if (full) STAGE(0, 0, 0, kt2);
    BAR; WLG; SB; MFMAQ(0, 0); BAR; SB;
    LDB2(1, 1);
    if (full) STAGE(0, 0, 1, kt2);
    BAR; WLG; SB; MFMAQ(0, 1); BAR; SB;
    LDA4(1, 1);
    if (full) STAGE(1, 1, 0, kt3);
    BAR; WLG; SB; MFMAQ(1, 0); BAR; SB;
    if (full) { STAGE(1, 1, 1, kt3); WVM4; }
    BAR; SB; MFMAQ(1, 1); BAR; SB;
  }

  const int r0 = rowBase + wm * 128 + g * 4;
  const int ymat = blockIdx.y >> 2;  // 0=q,1=k,2=v
  unsigned short* dst = (ymat == 0) ? O0 : ((ymat == 1) ? O1 : O2);
  const int c0 = (blockIdx.y & 3) * 256 + wn * 64 + frow;
  const bool doElu = (ymat < 2);
#pragma unroll
  for (int mi = 0; mi < 8; ++mi)
#pragma unroll
    for (int j = 0; j < 4; ++j) {
      const size_t ro = (size_t)(r0 + mi * 16 + j) * DD;
#pragma unroll
      for (int ni = 0; ni < 4; ++ni) {
        float v = acc[mi][ni][j];
        if (doElu) v = (v > 0.f) ? (v + 1.f) : __expf(v);
        dst[ro + c0 + ni * 16] = f2bf(v);
      }
    }
#undef STAGE
#undef LDA4
#undef LDB2
#undef MFMAQ
}

// ---------------- m97-style 128x128 GEMM, f32 out (O-projection, R2-exact) ----------------
__global__ __launch_bounds__(256, 2) void gemm_bt_f32(const unsigned short* __restrict__ A,
                                                      const unsigned short* __restrict__ Bw,
                                                      float* __restrict__ Cp,
                                                      int M, int N, int K) {
  constexpr int BM = 128, BN = 128, BK = 64;
  __shared__ unsigned short As[BM * BK];
  __shared__ unsigned short Bs[BN * BK];
  const int t = threadIdx.x;
  const int lane = t & 63;
  const int w = t >> 6;
  const int wr = w >> 1, wc = w & 1;
  const int rowBase = blockIdx.x * BM;
  const int colBase = blockIdx.y * BN;

  f32x4 acc[4][4];
#pragma unroll
  for (int i = 0; i < 4; ++i)
#pragma unroll
    for (int j = 0; j < 4; ++j) acc[i][j] = (f32x4){0.f, 0.f, 0.f, 0.f};

  const int sr = t >> 3;
  const int sc = (t & 7) * 8;
  const unsigned short* gA = A + (size_t)(rowBase + sr) * K + sc;
  const unsigned short* gB = Bw + (size_t)(colBase + sr) * K + sc;

  for (int k0 = 0; k0 < K; k0 += BK) {
#pragma unroll
    for (int i = 0; i < 4; ++i) {
      gload_lds16(gA + (size_t)i * 32 * K + k0, As + (i * 256 + w * 64) * 8);
      gload_lds16(gB + (size_t)i * 32 * K + k0, Bs + (i * 256 + w * 64) * 8);
    }
    __syncthreads();
#pragma unroll
    for (int kk = 0; kk < BK; kk += 32) {
      bf16x8 af[4], bfv[4];
#pragma unroll
      for (int mi = 0; mi < 4; ++mi)
        af[mi] = *(const bf16x8*)(As + (wr * 64 + mi * 16 + (lane & 15)) * BK + kk + (lane >> 4) * 8);
#pragma unroll
      for (int ni = 0; ni < 4; ++ni)
        bfv[ni] = *(const bf16x8*)(Bs + (wc * 64 + ni * 16 + (lane & 15)) * BK + kk + (lane >> 4) * 8);
#pragma unroll
      for (int mi = 0; mi < 4; ++mi)
#pragma unroll
        for (int ni = 0; ni < 4; ++ni)
          acc[mi][ni] = __builtin_amdgcn_mfma_f32_16x16x32_bf16(af[mi], bfv[ni], acc[mi][ni], 0, 0, 0);
    }
    __syncthreads();
  }

  const int r0 = rowBase + wr * 64 + ((lane >> 4) << 2);
  const int c0 = colBase + wc * 64 + (lane & 15);
#pragma unroll
  for (int mi = 0; mi < 4; ++mi)
#pragma unroll
    for (int j = 0; j < 4; ++j) {
      const size_t rowOff = (size_t)(r0 + mi * 16 + j) * N;
#pragma unroll
      for (int ni = 0; ni < 4; ++ni)
        Cp[rowOff + c0 + ni * 16] = acc[mi][ni][j];
    }
}

// ---------------- kv via MFMA: kvp[blk][d][m] = sum_n K[n][d] V[n][m]; ksp[blk][d] ----------------
// TN-GEMM per (b,h,chunk): A-frag = K^T gathered by ds_read_u16 (row d = lane&15,
// k-elems n = (lane>>4)*8+j), B-frag = V gathered identically (col m = lane&15).
// ksum via one extra MFMA with B = ones (every output column = sum_n K[n][d]).
__global__ __launch_bounds__(256) void kv_mfma(const unsigned short* __restrict__ Kb,
                                               const unsigned short* __restrict__ Vb,
                                               float* __restrict__ kvp,
                                               float* __restrict__ ksp) {
  __shared__ unsigned short kt[2][32 * 64];
  __shared__ unsigned short vt[2][32 * 64];
  const int blk = blockIdx.x;
  const int c = blk % KV_CHUNKS;
  const int h = (blk / KV_CHUNKS) % NHEAD;
  const int b = blk / (KV_CHUNKS * NHEAD);
  const int t = threadIdx.x;
  const int lane = t & 63;
  const int w = t >> 6;           // wave owns d-strip [w*16, w*16+16)
  const int frow = lane & 15;
  const int g = lane >> 4;
  const int chunkLen = NN / KV_CHUNKS;   // 256
  const int NSTEP = chunkLen / 32;       // 8

  const size_t base = ((size_t)b * NN + (size_t)c * chunkLen) * DD + h * HDIM;
  const unsigned short* sK = Kb + base + (size_t)(t >> 3) * DD + (t & 7) * 8;
  const unsigned short* sV = Vb + base + (size_t)(t >> 3) * DD + (t & 7) * 8;

  bf16x8 ones;
#pragma unroll
  for (int j = 0; j < 8; ++j) ones[j] = (short)0x3F80;  // bf16 1.0

  f32x4 acc[4], aks;
#pragma unroll
  for (int mt = 0; mt < 4; ++mt) acc[mt] = (f32x4){0.f, 0.f, 0.f, 0.f};
  aks = (f32x4){0.f, 0.f, 0.f, 0.f};

  // prologue: stage step 0
  gload_lds16(sK, &kt[0][t * 8]);
  gload_lds16(sV, &vt[0][t * 8]);

#pragma unroll 1
  for (int s = 0; s < NSTEP; ++s) {
    const int cur = s & 1;
    BAR;  // prior-iter reads of buf cur^1 complete before overwrite
    if (s + 1 < NSTEP) {
      gload_lds16(sK + (size_t)(s + 1) * 32 * DD, &kt[cur ^ 1][t * 8]);
      gload_lds16(sV + (size_t)(s + 1) * 32 * DD, &vt[cur ^ 1][t * 8]);
      WVM2;   // wait step-s pair (issued last iter / prologue); next pair stays in flight
    } else {
      WVM0;
    }
    BAR; SB;  // all waves' current tiles resident

    bf16x8 a;
#pragma unroll
    for (int j = 0; j < 8; ++j)
      a[j] = (short)kt[cur][(g * 8 + j) * 64 + w * 16 + frow];
#pragma unroll
    for (int mt = 0; mt < 4; ++mt) {
      bf16x8 bfr;
#pragma unroll
      for (int j = 0; j < 8; ++j)
        bfr[j] = (short)vt[cur][(g * 8 + j) * 64 + mt * 16 + frow];
      acc[mt] = __builtin_amdgcn_mfma_f32_16x16x32_bf16(a, bfr, acc[mt], 0, 0, 0);
    }
    aks = __builtin_amdgcn_mfma_f32_16x16x32_bf16(a, ones, aks, 0, 0, 0);
  }

  // C/D layout: col = lane&15 (=m sub), row = g*4+j (=d sub within wave strip)
  float* dst = kvp + (size_t)blk * 4096;
#pragma unroll
  for (int mt = 0; mt < 4; ++mt)
#pragma unroll
    for (int j = 0; j < 4; ++j)
      dst[(w * 16 + g * 4 + j) * 64 + mt * 16 + frow] = acc[mt][j];
  if (frow == 0) {
#pragma unroll
    for (int j = 0; j < 4; ++j)
      ksp[(size_t)blk * 64 + w * 16 + g * 4 + j] = aks[j];
  }
}

// ---------------- kv final: bf16 B-matrix kvb[bh][96][64]; row 64 = ksum ----------------
__global__ __launch_bounds__(256) void kv_final(const float* __restrict__ kvp,
                                                const float* __restrict__ ksp,
                                                unsigned short* __restrict__ kvb) {
  const int bh = blockIdx.x;
  const int t = threadIdx.x;
  __shared__ float kvs[4096];
#pragma unroll
  for (int e0 = 0; e0 < 4096; e0 += 256) {
    float s = 0.f;
    for (int cI = 0; cI < KV_CHUNKS; ++cI)
      s += kvp[((size_t)bh * KV_CHUNKS + cI) * 4096 + e0 + t];
    kvs[e0 + t] = s;
  }
  __syncthreads();
  unsigned short* dst = kvb + (size_t)bh * (96 * 64);
#pragma unroll
  for (int e0 = 0; e0 < 4096; e0 += 256) {
    int e = e0 + t;
    dst[e] = f2bf(kvs[(e & 63) * 64 + (e >> 6)]);
  }
  if (t < 64) {
    float s = 0.f;
    for (int cI = 0; cI < KV_CHUNKS; ++cI)
      s += ksp[((size_t)bh * KV_CHUNKS + cI) * 64 + t];
    dst[64 * 64 + t] = f2bf(s);
  }
  for (int e0 = 65 * 64; e0 < 96 * 64; e0 += 256) {
    int e = e0 + t;
    if (e < 96 * 64) dst[e] = 0;
  }
}

// ---------------- attn via MFMA ----------------
__global__ __launch_bounds__(256) void attn_mfma(const unsigned short* __restrict__ Qb,
                                                 const unsigned short* __restrict__ kvb,
                                                 unsigned short* __restrict__ Ob) {
  __shared__ unsigned short Bs[96 * 64];
  __shared__ unsigned short Qs[64 * 64];
  const int t = threadIdx.x;
  const int lane = t & 63;
  const int w = t >> 6;
  const int bh = blockIdx.y;
  const int b = bh >> 4;
  const int h = bh & 15;
  const int rowBase = blockIdx.x * 64;

  const unsigned short* bsrc = kvb + (size_t)bh * (96 * 64);
#pragma unroll
  for (int r = 0; r < 3; ++r) {
    int ci = r * 256 + t;
    int row = ci >> 3, ch = ci & 7;
    gload_lds16(bsrc + row * 64 + (ch ^ (row & 7)) * 8, Bs + ci * 8);
  }
  const int sr = t >> 3, ch0 = t & 7;
#pragma unroll
  for (int i = 0; i < 2; ++i) {
    int row = i * 32 + sr;
    const unsigned short* src =
        Qb + ((size_t)(b * NN + rowBase + row)) * DD + h * HDIM + (ch0 ^ (row & 7)) * 8;
    gload_lds16(src, Qs + row * 64 + ch0 * 8);
  }
  __syncthreads();

  const int frow = lane & 15;
  const int g = lane >> 4;
  bf16x8 a[2];
#pragma unroll
  for (int kk = 0; kk < 2; ++kk)
    a[kk] = *(const bf16x8*)(Qs + (w * 16 + frow) * 64 + ((kk * 4 + g) ^ (lane & 7)) * 8);

  f32x4 acc[5];
#pragma unroll
  for (int c = 0; c < 5; ++c) acc[c] = (f32x4){0.f, 0.f, 0.f, 0.f};
#pragma unroll
  for (int c = 0; c < 5; ++c) {
#pragma unroll
    for (int kk = 0; kk < 2; ++kk) {
      bf16x8 bf = *(const bf16x8*)(Bs + (c * 16 + frow) * 64 + ((kk * 4 + g) ^ (lane & 7)) * 8);
      acc[c] = __builtin_amdgcn_mfma_f32_16x16x32_bf16(a[kk], bf, acc[c], 0, 0, 0);
    }
  }

  float rden[4];
#pragma unroll
  for (int j = 0; j < 4; ++j) {
    float den = __shfl(acc[4][j], g * 16, 64);
    rden[j] = 1.f / (den + 1e-6f);
  }
  const size_t obase = ((size_t)(b * NN + rowBase + w * 16 + g * 4)) * DD + h * HDIM + frow;
#pragma unroll
  for (int c = 0; c < 4; ++c)
#pragma unroll
    for (int j = 0; j < 4; ++j)
      Ob[obase + (size_t)j * DD + c * 16] = f2bf(acc[c][j] * rden[j]);
}

// ---------------- launch ----------------
extern "C" void kernel_launch(void* const* d_in, const int* in_sizes, int n_in,
                              void* d_out, int out_size, void* d_ws, size_t ws_size,
                              hipStream_t stream) {
  const float* x  = (const float*)d_in[0];
  const float* Wq = (const float*)d_in[1];
  const float* Wk = (const float*)d_in[2];
  const float* Wv = (const float*)d_in[3];
  const float* Wo = (const float*)d_in[4];
  float* out = (float*)d_out;

  char* ws = (char*)d_ws;
  size_t off = 0;
  auto alloc = [&](size_t bytes) -> char* {
    char* p = ws + off;
    off += (bytes + 255) & ~(size_t)255;
    return p;
  };
  const size_t xN = (size_t)BB * NN * DD;  // 16777216
  unsigned short* xb   = (unsigned short*)alloc(xN * 2);
  unsigned short* qb   = (unsigned short*)alloc(xN * 2);
  unsigned short* kb   = (unsigned short*)alloc(xN * 2);
  unsigned short* vb   = (unsigned short*)alloc(xN * 2);
  unsigned short* wqkv = (unsigned short*)alloc((size_t)3 * DD * DD * 2);
  unsigned short* wob  = (unsigned short*)alloc((size_t)DD * DD * 2);
  float* ksp = (float*)alloc((size_t)BB * NHEAD * KV_CHUNKS * 64 * 4);
  unsigned short* kvb = (unsigned short*)alloc((size_t)BB * NHEAD * 96 * 64 * 2);
  // kvp (16.8 MB) aliases xb (33.5 MB): xb dead after QKV GEMM; kvp consumed by
  // kv_final before attn writes ob (= xb) — all stream-ordered.
  float* kvp = (float*)xb;
  unsigned short* ob = xb;

  f32_to_bf16_k<<<(int)(xN / (256 * 8)), 256, 0, stream>>>(x, xb);
  f32_to_bf16_k<<<(DD * DD) / (256 * 8), 256, 0, stream>>>(Wq, wqkv);
  f32_to_bf16_k<<<(DD * DD) / (256 * 8), 256, 0, stream>>>(Wk, wqkv + (size_t)DD * DD);
  f32_to_bf16_k<<<(DD * DD) / (256 * 8), 256, 0, stream>>>(Wv, wqkv + (size_t)2 * DD * DD);
  f32_to_bf16_k<<<(DD * DD) / (256 * 8), 256, 0, stream>>>(Wo, wob);

  dim3 gq(64, 12);  // M/256 x 3072/256
  gemm256_qkv<<<gq, 512, 0, stream>>>(xb, wqkv, qb, kb, vb);

  kv_mfma<<<BB * NHEAD * KV_CHUNKS, 256, 0, stream>>>(kb, vb, kvp, ksp);
  kv_final<<<BB * NHEAD, 256, 0, stream>>>(kvp, ksp, kvb);

  dim3 ga(NN / 64, BB * NHEAD);
  attn_mfma<<<ga, 256, 0, stream>>>(qb, kvb, ob);

  dim3 go(128, 8);  // m97 structure, R2-exact: M/128 x 1024/128
  gemm_bt_f32<<<go, 256, 0, stream>>>(ob, wob, out, BB * NN, DD, DD);
}

// Round 6
// 206.936 us; speedup vs baseline: 1.3651x; 1.1295x over previous
//
#include <hip/hip_runtime.h>
#include <stdint.h>

#define BB 2
#define NN 8192
#define DD 1024
#define KK 1024
#define NHEAD 16
#define HDIM 64
#define KV_CHUNKS 32

using f32x4  = __attribute__((ext_vector_type(4))) float;
using bf16x8 = __attribute__((ext_vector_type(8))) short;

__device__ __forceinline__ unsigned short f2bf(float f) {
  union { float f; unsigned int u; } v; v.f = f;
  unsigned int r = v.u + 0x7fffu + ((v.u >> 16) & 1u);
  return (unsigned short)(r >> 16);
}
__device__ __forceinline__ float bf2f(unsigned short u) {
  union { unsigned int u; float f; } v; v.u = ((unsigned int)u) << 16;
  return v.f;
}

__device__ __forceinline__ void gload_lds16(const unsigned short* g, unsigned short* l) {
  __builtin_amdgcn_global_load_lds(
      (__attribute__((address_space(1))) void*)(const_cast<unsigned short*>(g)),
      (__attribute__((address_space(3))) void*)(l), 16, 0, 0);
}

// ---------------- fused fp32 -> bf16 convert (x + 4 weights, 1 dispatch) ----------------
// Regions are multiples of 2048 elems -> branch is block-uniform.
__global__ __launch_bounds__(256) void convert_all(const float* __restrict__ x,
                                                   const float* __restrict__ Wq,
                                                   const float* __restrict__ Wk,
                                                   const float* __restrict__ Wv,
                                                   const float* __restrict__ Wo,
                                                   unsigned short* __restrict__ xb,
                                                   unsigned short* __restrict__ wqkv,
                                                   unsigned short* __restrict__ wob) {
  size_t i = ((size_t)blockIdx.x * 256 + threadIdx.x) * 8;
  const size_t xN = (size_t)BB * NN * DD;
  const float* src;
  unsigned short* dst;
  size_t off;
  if (i < xN) {
    src = x; dst = xb; off = i;
  } else {
    size_t r = i - xN;
    int wsel = (int)(r >> 20);          // 1048576 elems per weight
    off = r & 1048575;
    src = (wsel == 0) ? Wq : (wsel == 1) ? Wk : (wsel == 2) ? Wv : Wo;
    dst = (wsel < 3) ? (wqkv + (size_t)wsel * 1048576) : wob;
  }
  float4 a = *(const float4*)(src + off);
  float4 b = *(const float4*)(src + off + 4);
  uint32_t p0 = (uint32_t)f2bf(a.x) | ((uint32_t)f2bf(a.y) << 16);
  uint32_t p1 = (uint32_t)f2bf(a.z) | ((uint32_t)f2bf(a.w) << 16);
  uint32_t p2 = (uint32_t)f2bf(b.x) | ((uint32_t)f2bf(b.y) << 16);
  uint32_t p3 = (uint32_t)f2bf(b.z) | ((uint32_t)f2bf(b.w) << 16);
  *(uint4*)(dst + off) = make_uint4(p0, p1, p2, p3);
}

// ---------------- 256x256 8-phase GEMM: C = A[M,K] * B[N,K]^T ----------------
// EPI 0: fused QKV (N=3072, col-block -> q/k/v, elu on q/k, bf16 out)
// EPI 1: plain f32 out (N=1024)
// vmcnt gate placed AFTER the P4/P8 MFMA quadrant (stall hidden under MFMA; gate
// invariant unchanged: buffer resident after the phase-closing barrier).
#define BAR  __builtin_amdgcn_s_barrier()
#define SB   __builtin_amdgcn_sched_barrier(0)
#define WLG  asm volatile("s_waitcnt lgkmcnt(0)" ::: "memory")
#define WVM4 asm volatile("s_waitcnt vmcnt(4)" ::: "memory")
#define WVM0 asm volatile("s_waitcnt vmcnt(0)" ::: "memory")

template <int EPI>
__global__ __launch_bounds__(512, 2) void gemm256(const unsigned short* __restrict__ A,
                                                  const unsigned short* __restrict__ Bw,
                                                  unsigned short* __restrict__ O0,
                                                  unsigned short* __restrict__ O1,
                                                  unsigned short* __restrict__ O2,
                                                  float* __restrict__ OF) {
  __shared__ unsigned short lds[2][2][2][128 * 64];  // [dbuf][A/B][half][128x64] = 128 KB
  const int t = threadIdx.x;
  const int lane = t & 63;
  const int w = t >> 6;
  const int wm = w >> 2;
  const int wn = w & 3;
  const int frow = lane & 15;
  const int g = lane >> 4;
  const int fx = frow & 7;
  const int rowBase = blockIdx.x * 256;
  const int colBase = blockIdx.y * 256;

  const int srow0 = t >> 3;
  const int ssw = ((t & 7) ^ (srow0 & 7)) * 8;
  const unsigned short* sA0 = A + (size_t)(rowBase + srow0) * KK + ssw;
  const unsigned short* sA1 = A + (size_t)(rowBase + 64 + srow0) * KK + ssw;
  const unsigned short* sB0 = Bw + (size_t)(colBase + srow0) * KK + ssw;
  const unsigned short* sB1 = Bw + (size_t)(colBase + 64 + srow0) * KK + ssw;

#define STAGE(db, ab, half, kt)                                                        \
  do {                                                                                 \
    gload_lds16(((ab) ? sB0 : sA0) + (size_t)(half) * 128 * KK + (size_t)(kt) * 64,    \
                &lds[db][ab][half][(0 * 512 + w * 64) * 8]);                           \
    gload_lds16(((ab) ? sB1 : sA1) + (size_t)(half) * 128 * KK + (size_t)(kt) * 64,    \
                &lds[db][ab][half][(1 * 512 + w * 64) * 8]);                           \
  } while (0)

  bf16x8 ar[4][2], br[4][2];
  f32x4 acc[8][4];
#pragma unroll
  for (int i = 0; i < 8; ++i)
#pragma unroll
    for (int j = 0; j < 4; ++j) acc[i][j] = (f32x4){0.f, 0.f, 0.f, 0.f};

#define LDA4(db, mih)                                                                  \
  _Pragma("unroll") for (int mi2 = 0; mi2 < 4; ++mi2)                                  \
  _Pragma("unroll") for (int kk2 = 0; kk2 < 2; ++kk2)                                  \
    ar[mi2][kk2] = *(const bf16x8*)((const char*)&lds[db][0][wm][0] +                  \
        ((mih) * 64 + mi2 * 16 + frow) * 128 + ((kk2 * 4 + g) ^ fx) * 16);

#define LDB2(db, nih)                                                                  \
  _Pragma("unroll") for (int ni2 = 0; ni2 < 2; ++ni2)                                  \
  _Pragma("unroll") for (int kk2 = 0; kk2 < 2; ++kk2)                                  \
    br[(nih) * 2 + ni2][kk2] = *(const bf16x8*)((const char*)&lds[db][1][wn >> 1][0] + \
        ((wn & 1) * 64 + (nih) * 32 + ni2 * 16 + frow) * 128 + ((kk2 * 4 + g) ^ fx) * 16);

#define MFMAQ(mih, nih)                                                                \
  __builtin_amdgcn_s_setprio(1);                                                      \
  _Pragma("unroll") for (int mi2 = 0; mi2 < 4; ++mi2)                                  \
  _Pragma("unroll") for (int ni2 = 0; ni2 < 2; ++ni2)                                  \
  _Pragma("unroll") for (int kk2 = 0; kk2 < 2; ++kk2)                                  \
    acc[(mih) * 4 + mi2][(nih) * 2 + ni2] = __builtin_amdgcn_mfma_f32_16x16x32_bf16(   \
        ar[mi2][kk2], br[(nih) * 2 + ni2][kk2],                                        \
        acc[(mih) * 4 + mi2][(nih) * 2 + ni2], 0, 0, 0);                               \
  __builtin_amdgcn_s_setprio(0);

  STAGE(0, 1, 0, 0); STAGE(0, 1, 1, 0);
  STAGE(0, 0, 0, 0); STAGE(0, 0, 1, 0);
  STAGE(1, 1, 0, 1); STAGE(1, 1, 1, 1);
  WVM4; BAR; SB;

#pragma unroll 1
  for (int i = 0; i < 8; ++i) {
    const bool full = (i < 7);
    const int kt1 = 2 * i + 1, kt2 = 2 * i + 2, kt3 = 2 * i + 3;
    LDA4(0, 0); LDB2(0, 0);
    STAGE(1, 0, 0, kt1);
    BAR; WLG; SB; MFMAQ(0, 0); BAR; SB;
    LDB2(0, 1);
    STAGE(1, 0, 1, kt1);
    BAR; WLG; SB; MFMAQ(0, 1); BAR; SB;
    LDA4(0, 1);
    if (full) STAGE(0, 1, 0, kt2);
    BAR; WLG; SB; MFMAQ(1, 0); BAR; SB;
    // P4: gate moved after the quadrant
    if (full) STAGE(0, 1, 1, kt2);
    BAR; SB; MFMAQ(1, 1);
    if (full) { WVM4; } else { WVM0; }
    BAR; SB;
    LDA4(1, 0); LDB2(1, 0);
    if (full) STAGE(0, 0, 0, kt2);
    BAR; WLG; SB; MFMAQ(0, 0); BAR; SB;
    LDB2(1, 1);
    if (full) STAGE(0, 0, 1, kt2);
    BAR; WLG; SB; MFMAQ(0, 1); BAR; SB;
    LDA4(1, 1);
    if (full) STAGE(1, 1, 0, kt3);
    BAR; WLG; SB; MFMAQ(1, 0); BAR; SB;
    // P8: gate moved after the quadrant
    if (full) STAGE(1, 1, 1, kt3);
    BAR; SB; MFMAQ(1, 1);
    if (full) { WVM4; }
    BAR; SB;
  }

  const int r0 = rowBase + wm * 128 + g * 4;
  if constexpr (EPI == 0) {
    const int ymat = blockIdx.y >> 2;  // 0=q,1=k,2=v
    unsigned short* dst = (ymat == 0) ? O0 : ((ymat == 1) ? O1 : O2);
    const int c0 = (blockIdx.y & 3) * 256 + wn * 64 + frow;
    const bool doElu = (ymat < 2);
#pragma unroll
    for (int mi = 0; mi < 8; ++mi)
#pragma unroll
      for (int j = 0; j < 4; ++j) {
        const size_t ro = (size_t)(r0 + mi * 16 + j) * DD;
#pragma unroll
        for (int ni = 0; ni < 4; ++ni) {
          float v = acc[mi][ni][j];
          if (doElu) v = (v > 0.f) ? (v + 1.f) : __expf(v);
          dst[ro + c0 + ni * 16] = f2bf(v);
        }
      }
  } else {
    const int c0 = colBase + wn * 64 + frow;
#pragma unroll
    for (int mi = 0; mi < 8; ++mi)
#pragma unroll
      for (int j = 0; j < 4; ++j) {
        const size_t ro = (size_t)(r0 + mi * 16 + j) * DD;
#pragma unroll
        for (int ni = 0; ni < 4; ++ni)
          OF[ro + c0 + ni * 16] = acc[mi][ni][j];
      }
  }
#undef STAGE
#undef LDA4
#undef LDB2
#undef MFMAQ
}

// ---------------- kv via MFMA: kvp[blk][d][m] = sum_n K[n][d] V[n][m]; ksp[blk][d] ----------------
__global__ __launch_bounds__(256) void kv_mfma(const unsigned short* __restrict__ Kb,
                                               const unsigned short* __restrict__ Vb,
                                               float* __restrict__ kvp,
                                               float* __restrict__ ksp) {
  __shared__ unsigned short kt[2][32 * 64];
  __shared__ unsigned short vt[2][32 * 64];
  const int blk = blockIdx.x;
  const int c = blk % KV_CHUNKS;
  const int h = (blk / KV_CHUNKS) % NHEAD;
  const int b = blk / (KV_CHUNKS * NHEAD);
  const int t = threadIdx.x;
  const int lane = t & 63;
  const int w = t >> 6;
  const int frow = lane & 15;
  const int g = lane >> 4;
  const int chunkLen = NN / KV_CHUNKS;   // 256
  const int NSTEP = chunkLen / 32;       // 8

  const size_t base = ((size_t)b * NN + (size_t)c * chunkLen) * DD + h * HDIM;
  const unsigned short* sK = Kb + base + (size_t)(t >> 3) * DD + (t & 7) * 8;
  const unsigned short* sV = Vb + base + (size_t)(t >> 3) * DD + (t & 7) * 8;

  bf16x8 ones;
#pragma unroll
  for (int j = 0; j < 8; ++j) ones[j] = (short)0x3F80;

  f32x4 acc[4], aks;
#pragma unroll
  for (int mt = 0; mt < 4; ++mt) acc[mt] = (f32x4){0.f, 0.f, 0.f, 0.f};
  aks = (f32x4){0.f, 0.f, 0.f, 0.f};

  gload_lds16(sK, &kt[0][t * 8]);
  gload_lds16(sV, &vt[0][t * 8]);

#pragma unroll 1
  for (int s = 0; s < NSTEP; ++s) {
    const int cur = s & 1;
    BAR;
    if (s + 1 < NSTEP) {
      gload_lds16(sK + (size_t)(s + 1) * 32 * DD, &kt[cur ^ 1][t * 8]);
      gload_lds16(sV + (size_t)(s + 1) * 32 * DD, &vt[cur ^ 1][t * 8]);
      asm volatile("s_waitcnt vmcnt(2)" ::: "memory");
    } else {
      WVM0;
    }
    BAR; SB;

    bf16x8 a;
#pragma unroll
    for (int j = 0; j < 8; ++j)
      a[j] = (short)kt[cur][(g * 8 + j) * 64 + w * 16 + frow];
#pragma unroll
    for (int mt = 0; mt < 4; ++mt) {
      bf16x8 bfr;
#pragma unroll
      for (int j = 0; j < 8; ++j)
        bfr[j] = (short)vt[cur][(g * 8 + j) * 64 + mt * 16 + frow];
      acc[mt] = __builtin_amdgcn_mfma_f32_16x16x32_bf16(a, bfr, acc[mt], 0, 0, 0);
    }
    aks = __builtin_amdgcn_mfma_f32_16x16x32_bf16(a, ones, aks, 0, 0, 0);
  }

  float* dst = kvp + (size_t)blk * 4096;
#pragma unroll
  for (int mt = 0; mt < 4; ++mt)
#pragma unroll
    for (int j = 0; j < 4; ++j)
      dst[(w * 16 + g * 4 + j) * 64 + mt * 16 + frow] = acc[mt][j];
  if (frow == 0) {
#pragma unroll
    for (int j = 0; j < 4; ++j)
      ksp[(size_t)blk * 64 + w * 16 + g * 4 + j] = aks[j];
  }
}

// ---------------- kv final: bf16 B-matrix kvb[bh][96][64]; row 64 = ksum ----------------
__global__ __launch_bounds__(256) void kv_final(const float* __restrict__ kvp,
                                                const float* __restrict__ ksp,
                                                unsigned short* __restrict__ kvb) {
  const int bh = blockIdx.x;
  const int t = threadIdx.x;
  __shared__ float kvs[4096];
#pragma unroll
  for (int e0 = 0; e0 < 4096; e0 += 256) {
    float s = 0.f;
    for (int cI = 0; cI < KV_CHUNKS; ++cI)
      s += kvp[((size_t)bh * KV_CHUNKS + cI) * 4096 + e0 + t];
    kvs[e0 + t] = s;
  }
  __syncthreads();
  unsigned short* dst = kvb + (size_t)bh * (96 * 64);
#pragma unroll
  for (int e0 = 0; e0 < 4096; e0 += 256) {
    int e = e0 + t;
    dst[e] = f2bf(kvs[(e & 63) * 64 + (e >> 6)]);
  }
  if (t < 64) {
    float s = 0.f;
    for (int cI = 0; cI < KV_CHUNKS; ++cI)
      s += ksp[((size_t)bh * KV_CHUNKS + cI) * 64 + t];
    dst[64 * 64 + t] = f2bf(s);
  }
  for (int e0 = 65 * 64; e0 < 96 * 64; e0 += 256) {
    int e = e0 + t;
    if (e < 96 * 64) dst[e] = 0;
  }
}

// ---------------- attn via MFMA: 128 rows/block, B-frags reused across row-halves ----------------
__global__ __launch_bounds__(256) void attn_mfma(const unsigned short* __restrict__ Qb,
                                                 const unsigned short* __restrict__ kvb,
                                                 unsigned short* __restrict__ Ob) {
  __shared__ unsigned short Bs[96 * 64];
  __shared__ unsigned short Qs[128 * 64];
  const int t = threadIdx.x;
  const int lane = t & 63;
  const int w = t >> 6;
  const int bh = blockIdx.y;
  const int b = bh >> 4;
  const int h = bh & 15;
  const int rowBase = blockIdx.x * 128;

  const unsigned short* bsrc = kvb + (size_t)bh * (96 * 64);
#pragma unroll
  for (int r = 0; r < 3; ++r) {
    int ci = r * 256 + t;
    int row = ci >> 3, ch = ci & 7;
    gload_lds16(bsrc + row * 64 + (ch ^ (row & 7)) * 8, Bs + ci * 8);
  }
  const int sr = t >> 3, ch0 = t & 7;
#pragma unroll
  for (int i = 0; i < 4; ++i) {
    int row = i * 32 + sr;
    const unsigned short* src =
        Qb + ((size_t)(b * NN + rowBase + row)) * DD + h * HDIM + (ch0 ^ (row & 7)) * 8;
    gload_lds16(src, Qs + row * 64 + ch0 * 8);
  }
  __syncthreads();

  const int frow = lane & 15;
  const int g = lane >> 4;
  bf16x8 a[2][2];
#pragma unroll
  for (int rb = 0; rb < 2; ++rb)
#pragma unroll
    for (int kk = 0; kk < 2; ++kk)
      a[rb][kk] = *(const bf16x8*)(Qs + (rb * 64 + w * 16 + frow) * 64 + ((kk * 4 + g) ^ (lane & 7)) * 8);

  f32x4 acc[2][5];
#pragma unroll
  for (int rb = 0; rb < 2; ++rb)
#pragma unroll
    for (int c = 0; c < 5; ++c) acc[rb][c] = (f32x4){0.f, 0.f, 0.f, 0.f};
#pragma unroll
  for (int c = 0; c < 5; ++c) {
#pragma unroll
    for (int kk = 0; kk < 2; ++kk) {
      bf16x8 bf = *(const bf16x8*)(Bs + (c * 16 + frow) * 64 + ((kk * 4 + g) ^ (lane & 7)) * 8);
#pragma unroll
      for (int rb = 0; rb < 2; ++rb)
        acc[rb][c] = __builtin_amdgcn_mfma_f32_16x16x32_bf16(a[rb][kk], bf, acc[rb][c], 0, 0, 0);
    }
  }

#pragma unroll
  for (int rb = 0; rb < 2; ++rb) {
    float rden[4];
#pragma unroll
    for (int j = 0; j < 4; ++j) {
      float den = __shfl(acc[rb][4][j], g * 16, 64);
      rden[j] = 1.f / (den + 1e-6f);
    }
    const size_t obase =
        ((size_t)(b * NN + rowBase + rb * 64 + w * 16 + g * 4)) * DD + h * HDIM + frow;
#pragma unroll
    for (int c = 0; c < 4; ++c)
#pragma unroll
      for (int j = 0; j < 4; ++j)
        Ob[obase + (size_t)j * DD + c * 16] = f2bf(acc[rb][c][j] * rden[j]);
  }
}

// ---------------- launch ----------------
extern "C" void kernel_launch(void* const* d_in, const int* in_sizes, int n_in,
                              void* d_out, int out_size, void* d_ws, size_t ws_size,
                              hipStream_t stream) {
  const float* x  = (const float*)d_in[0];
  const float* Wq = (const float*)d_in[1];
  const float* Wk = (const float*)d_in[2];
  const float* Wv = (const float*)d_in[3];
  const float* Wo = (const float*)d_in[4];
  float* out = (float*)d_out;

  char* ws = (char*)d_ws;
  size_t off = 0;
  auto alloc = [&](size_t bytes) -> char* {
    char* p = ws + off;
    off += (bytes + 255) & ~(size_t)255;
    return p;
  };
  const size_t xN = (size_t)BB * NN * DD;  // 16777216
  unsigned short* xb   = (unsigned short*)alloc(xN * 2);
  unsigned short* qb   = (unsigned short*)alloc(xN * 2);
  unsigned short* kb   = (unsigned short*)alloc(xN * 2);
  unsigned short* vb   = (unsigned short*)alloc(xN * 2);
  unsigned short* wqkv = (unsigned short*)alloc((size_t)3 * DD * DD * 2);
  unsigned short* wob  = (unsigned short*)alloc((size_t)DD * DD * 2);
  float* ksp = (float*)alloc((size_t)BB * NHEAD * KV_CHUNKS * 64 * 4);
  unsigned short* kvb = (unsigned short*)alloc((size_t)BB * NHEAD * 96 * 64 * 2);
  // kvp (16.8 MB) aliases xb (33.5 MB): xb dead after QKV GEMM; kvp consumed by
  // kv_final before attn writes ob (= xb) — all stream-ordered.
  float* kvp = (float*)xb;
  unsigned short* ob = xb;

  const int convBlocks = (int)((xN + 4 * 1048576) / 2048);  // 10240
  convert_all<<<convBlocks, 256, 0, stream>>>(x, Wq, Wk, Wv, Wo, xb, wqkv, wob);

  dim3 gq(64, 12);  // M/256 x 3072/256
  gemm256<0><<<gq, 512, 0, stream>>>(xb, wqkv, qb, kb, vb, nullptr);

  kv_mfma<<<BB * NHEAD * KV_CHUNKS, 256, 0, stream>>>(kb, vb, kvp, ksp);
  kv_final<<<BB * NHEAD, 256, 0, stream>>>(kvp, ksp, kvb);

  dim3 ga(NN / 128, BB * NHEAD);
  attn_mfma<<<ga, 256, 0, stream>>>(qb, kvb, ob);

  dim3 go(64, 4);  // M/256 x 1024/256, 8-phase structure
  gemm256<1><<<go, 512, 0, stream>>>(ob, wob, nullptr, nullptr, nullptr, out);
}